// Round 2
// baseline (557.487 us; speedup 1.0000x reference)
//
#include <hip/hip_runtime.h>
#include <math.h>

typedef unsigned short u16;
using bf16x8 = __attribute__((ext_vector_type(8))) short;
using f32x4  = __attribute__((ext_vector_type(4))) float;

#define DD 4096
#define NB 256            // batch
#define SPLIT_K 4
#define PSTRIDE (NB * DD) // floats per partial buffer

__device__ __forceinline__ u16 f2bf(float f) {
  unsigned int u = __float_as_uint(f);
  u += 0x7fffu + ((u >> 16) & 1u);   // RNE
  return (u16)(u >> 16);
}
__device__ __forceinline__ unsigned int pack2bf(float a, float b) {
  return (unsigned int)f2bf(a) | ((unsigned int)f2bf(b) << 16);
}
__device__ __forceinline__ void async_cp16(const u16* g, u16* l) {
  __builtin_amdgcn_global_load_lds(
      (const __attribute__((address_space(1))) unsigned int*)g,
      (__attribute__((address_space(3))) unsigned int*)l, 16, 0, 0);
}

// ---------------------------------------------------------------------------
// GEMM: part[kz] = Xf(bf16) @ W^T over K-chunk kz.  M=256 full per WG.
// grid (64 n-tiles, 4 k-splits), 512 threads (8 waves). Tile 256x64, BK=64.
// W is read fp32 (streamed once from HBM), converted to bf16 in-register.
// A staged via global_load_lds(16B) with XOR-chunk swizzle on the SOURCE addr.
// ---------------------------------------------------------------------------
__global__ __launch_bounds__(512) void gemm_kernel(
    const u16* __restrict__ A, const float* __restrict__ W,
    float* __restrict__ part)
{
  const int nt = blockIdx.x;
  const int kz = blockIdx.y;
  const int t = threadIdx.x;
  const int w = t >> 6, l = t & 63;

  __shared__ __align__(16) u16 As[256 * 64];
  __shared__ __align__(16) u16 Bs[64 * 64];

  const int colg0 = nt << 6;
  const int k0 = kz << 10;

  f32x4 acc[4][2];
#pragma unroll
  for (int mi = 0; mi < 4; ++mi)
#pragma unroll
    for (int nj = 0; nj < 2; ++nj)
      acc[mi][nj] = (f32x4){0.f, 0.f, 0.f, 0.f};

  const int wm = w & 3, wn = w >> 2;      // wave tile: rows 64*wm, cols 32*wn
  const int lr = l & 15, lg = l >> 4;
  const int arow_l = (w << 3) + (l >> 3); // A stage row (per rep +64)
  const int acl = l & 7;                  // linear chunk within row
  const int bn_l = t >> 3;                // B stage: W row (output col)
  const int bcc = t & 7;                  // B stage: chunk

  for (int kk = 0; kk < 1024; kk += 64) {
    __syncthreads();
    // stage A: 256x64 bf16, linear LDS dest, source chunk pre-swizzled
#pragma unroll
    for (int r = 0; r < 4; ++r) {
      const int row = (r << 6) + arow_l;
      const int cs = acl ^ (row & 7);
      async_cp16(A + ((size_t)row << 12) + (k0 + kk) + (cs << 3),
                 As + (r << 12) + (w << 9));
    }
    // stage B: 64(row=out col) x 64(k) fp32 -> bf16, swizzled ds_write
    {
      const float* wsrc = W + ((size_t)(colg0 + bn_l) << 12) + (k0 + kk) + (bcc << 3);
      const float4 f0 = *reinterpret_cast<const float4*>(wsrc);
      const float4 f1 = *reinterpret_cast<const float4*>(wsrc + 4);
      uint4 pk;
      pk.x = pack2bf(f0.x, f0.y);
      pk.y = pack2bf(f0.z, f0.w);
      pk.z = pack2bf(f1.x, f1.y);
      pk.w = pack2bf(f1.z, f1.w);
      *reinterpret_cast<uint4*>(&Bs[(bn_l << 6) + ((bcc ^ (bn_l & 7)) << 3)]) = pk;
    }
    __syncthreads();
#pragma unroll
    for (int ks = 0; ks < 2; ++ks) {
      const int cg = (ks << 2) + lg;
      bf16x8 av[4], bv[2];
#pragma unroll
      for (int mi = 0; mi < 4; ++mi) {
        const int fr = (wm << 6) + (mi << 4) + lr;
        av[mi] = *reinterpret_cast<const bf16x8*>(&As[(fr << 6) + ((cg ^ (fr & 7)) << 3)]);
      }
#pragma unroll
      for (int nj = 0; nj < 2; ++nj) {
        const int fc = (wn << 5) + (nj << 4) + lr;
        bv[nj] = *reinterpret_cast<const bf16x8*>(&Bs[(fc << 6) + ((cg ^ (fc & 7)) << 3)]);
      }
#pragma unroll
      for (int mi = 0; mi < 4; ++mi)
#pragma unroll
        for (int nj = 0; nj < 2; ++nj)
          acc[mi][nj] = __builtin_amdgcn_mfma_f32_16x16x32_bf16(
              av[mi], bv[nj], acc[mi][nj], 0, 0, 0);
    }
  }

  float* pout = part + (size_t)kz * PSTRIDE;
#pragma unroll
  for (int mi = 0; mi < 4; ++mi)
#pragma unroll
    for (int nj = 0; nj < 2; ++nj) {
      const int col = colg0 + (wn << 5) + (nj << 4) + lr;
#pragma unroll
      for (int j = 0; j < 4; ++j) {
        const int row = (wm << 6) + (mi << 4) + (lg << 2) + j;
        pout[((size_t)row << 12) + col] = acc[mi][nj][j];
      }
    }
}

// ---------------------------------------------------------------------------
// Per-sample Stiefel update.  Cayley collapsed analytically:
//   new_A = A - H^2 * F @ (A^T F) @ (A^T A)      (exact to fp32; H^4 ~ 1e-13)
// ---------------------------------------------------------------------------
__device__ __forceinline__ void stiefel_update(
    float (&Am)[64][17], float (&Dm)[64][17], float (&Fm)[64][17],
    float (&T1)[16][17], float (&G1)[16][17], float (&G2)[16][17],
    float (&M1)[16][17], int t, float* __restrict__ gout, size_t ub)
{
  const int p4 = t >> 2, e4 = (t & 3) << 2;
  const int i16 = t >> 4, j16 = t & 15;
  // T1 = A^T D
  {
    float a = 0.f;
    for (int r = 0; r < 64; ++r) a += Am[r][i16] * Dm[r][j16];
    T1[i16][j16] = a;
  }
  __syncthreads();
  // F = D - A @ T1
#pragma unroll
  for (int e = 0; e < 4; ++e) {
    float a = Dm[p4][e4 + e];
    for (int j = 0; j < 16; ++j) a -= Am[p4][j] * T1[j][e4 + e];
    Fm[p4][e4 + e] = a;
  }
  __syncthreads();
  // G1 = A^T F ; G2 = A^T A
  {
    float g1 = 0.f, g2 = 0.f;
    for (int r = 0; r < 64; ++r) {
      g1 += Am[r][i16] * Fm[r][j16];
      g2 += Am[r][i16] * Am[r][j16];
    }
    G1[i16][j16] = g1;
    G2[i16][j16] = g2;
  }
  __syncthreads();
  // M1 = G1 @ G2
  {
    float m = 0.f;
    for (int k = 0; k < 16; ++k) m += G1[i16][k] * G2[k][j16];
    M1[i16][j16] = m;
  }
  __syncthreads();
  // A -= H^2 * F @ M1
#pragma unroll
  for (int e = 0; e < 4; ++e) {
    float a = 0.f;
    for (int j = 0; j < 16; ++j) a += Fm[p4][j] * M1[j][e4 + e];
    const float nv = Am[p4][e4 + e] - 1e-6f * a;
    Am[p4][e4 + e] = nv;
    gout[ub + ((size_t)p4 << 4) + e4 + e] = nv;
  }
  __syncthreads();
}

__global__ __launch_bounds__(256) void update_kernel(
    const float* __restrict__ part, const float* __restrict__ bias,
    float* __restrict__ u_g, float* __restrict__ v_g, float* __restrict__ s_g,
    float* __restrict__ Xf, u16* __restrict__ Xfb,
    float* __restrict__ outT, int layer)
{
  const int b = blockIdx.x, t = threadIdx.x;
  __shared__ float dY[64][65];
  __shared__ float U[64][17], V[64][17];
  __shared__ float P[64][17], Q[64][17], F[64][17];
  __shared__ float S[16][16], dSs[16][17], T1[16][17], G1[16][17], G2[16][17], M1[16][17];
  __shared__ float sinv[16];

  const size_t ub = (size_t)b << 10;
  {
    const float4 u4 = *reinterpret_cast<const float4*>(u_g + ub + (t << 2));
    const float4 v4 = *reinterpret_cast<const float4*>(v_g + ub + (t << 2));
    const int r = t >> 2, c = (t & 3) << 2;
    U[r][c] = u4.x; U[r][c + 1] = u4.y; U[r][c + 2] = u4.z; U[r][c + 3] = u4.w;
    V[r][c] = v4.x; V[r][c + 1] = v4.y; V[r][c + 2] = v4.z; V[r][c + 3] = v4.w;
    S[t >> 4][t & 15] = s_g[((size_t)b << 8) + t];
  }
  __syncthreads();
  if (t < 16) sinv[t] = 1.0f / S[t][t];
  // dY = relu(sum of 4 partials + bias)
  {
    const float* p0 = part + ((size_t)b << 12);
#pragma unroll
    for (int it = 0; it < 4; ++it) {
      const int i = (it << 8) + t;  // float4 index 0..1023
      const float4 a0 = *reinterpret_cast<const float4*>(p0 + (i << 2));
      const float4 a1 = *reinterpret_cast<const float4*>(p0 + PSTRIDE + (i << 2));
      const float4 a2 = *reinterpret_cast<const float4*>(p0 + 2 * PSTRIDE + (i << 2));
      const float4 a3 = *reinterpret_cast<const float4*>(p0 + 3 * PSTRIDE + (i << 2));
      float x0 = a0.x + a1.x + a2.x + a3.x;
      float x1 = a0.y + a1.y + a2.y + a3.y;
      float x2 = a0.z + a1.z + a2.z + a3.z;
      float x3 = a0.w + a1.w + a2.w + a3.w;
      if (bias != nullptr) {
        const float4 bb = *reinterpret_cast<const float4*>(bias + (i << 2));
        x0 += bb.x; x1 += bb.y; x2 += bb.z; x3 += bb.w;
      }
      const int r = i >> 4, c = (i & 15) << 2;
      dY[r][c]     = fmaxf(x0, 0.f);
      dY[r][c + 1] = fmaxf(x1, 0.f);
      dY[r][c + 2] = fmaxf(x2, 0.f);
      dY[r][c + 3] = fmaxf(x3, 0.f);
    }
  }
  __syncthreads();
  const int p4 = t >> 2, e4 = (t & 3) << 2;
  const int i16 = t >> 4, j16 = t & 15;
  // P = dY @ V (Dv) ; Q = dY^T @ U (Du)
  {
    float a0 = 0, a1 = 0, a2 = 0, a3 = 0;
    for (int q = 0; q < 64; ++q) {
      const float d = dY[p4][q];
      a0 += d * V[q][e4]; a1 += d * V[q][e4 + 1];
      a2 += d * V[q][e4 + 2]; a3 += d * V[q][e4 + 3];
    }
    P[p4][e4] = a0; P[p4][e4 + 1] = a1; P[p4][e4 + 2] = a2; P[p4][e4 + 3] = a3;
    float b0 = 0, b1 = 0, b2 = 0, b3 = 0;
    for (int r = 0; r < 64; ++r) {
      const float d = dY[r][p4];
      b0 += d * U[r][e4]; b1 += d * U[r][e4 + 1];
      b2 += d * U[r][e4 + 2]; b3 += d * U[r][e4 + 3];
    }
    Q[p4][e4] = b0; Q[p4][e4 + 1] = b1; Q[p4][e4 + 2] = b2; Q[p4][e4 + 3] = b3;
  }
  __syncthreads();
  // dS = U^T @ P (unscaled Dv)
  {
    float a = 0.f;
    for (int r = 0; r < 64; ++r) a += U[r][i16] * P[r][j16];
    dSs[i16][j16] = a;
  }
  __syncthreads();
  // scale by s_inv diag: P -> dU, Q -> dV
  for (int i = t; i < 1024; i += 256) {
    const int r = i >> 4, c = i & 15;
    const float sc = sinv[c];
    P[r][c] *= sc;
    Q[r][c] *= sc;
  }
  __syncthreads();

  stiefel_update(U, P, F, T1, G1, G2, M1, t, u_g, ub);
  stiefel_update(V, Q, F, T1, G1, G2, M1, t, v_g, ub);

  // s += H * dS
  {
    const float ns = S[i16][j16] + 1e-3f * dSs[i16][j16];
    S[i16][j16] = ns;
    s_g[((size_t)b << 8) + t] = ns;
  }
  __syncthreads();
  // us = U @ S  (reuse P)
#pragma unroll
  for (int e = 0; e < 4; ++e) {
    float a = 0.f;
    for (int i = 0; i < 16; ++i) a += U[p4][i] * S[i][e4 + e];
    P[p4][e4 + e] = a;
  }
  __syncthreads();
  // Xf[p][q] = sum_i us[p][i] * V[q][i]  ; write f32, bf16, strided transform out
  {
    const int q0 = (t & 3) << 4;
    float res[16];
#pragma unroll
    for (int qq = 0; qq < 16; ++qq) {
      float a = 0.f;
      for (int i = 0; i < 16; ++i) a += P[p4][i] * V[q0 + qq][i];
      res[qq] = a;
    }
    const size_t ko = ((size_t)b << 12) + (p4 << 6) + q0;
    float4* xo = reinterpret_cast<float4*>(Xf + ko);
    xo[0] = make_float4(res[0], res[1], res[2], res[3]);
    xo[1] = make_float4(res[4], res[5], res[6], res[7]);
    xo[2] = make_float4(res[8], res[9], res[10], res[11]);
    xo[3] = make_float4(res[12], res[13], res[14], res[15]);
    uint4 pk0, pk1;
    pk0.x = pack2bf(res[0], res[1]);   pk0.y = pack2bf(res[2], res[3]);
    pk0.z = pack2bf(res[4], res[5]);   pk0.w = pack2bf(res[6], res[7]);
    pk1.x = pack2bf(res[8], res[9]);   pk1.y = pack2bf(res[10], res[11]);
    pk1.z = pack2bf(res[12], res[13]); pk1.w = pack2bf(res[14], res[15]);
    *reinterpret_cast<uint4*>(Xfb + ko) = pk0;
    *reinterpret_cast<uint4*>(Xfb + ko + 8) = pk1;
    float* op = outT + ko * 9 + layer;
#pragma unroll
    for (int qq = 0; qq < 16; ++qq) op[qq * 9] = res[qq];
  }
}

// ---------------------------------------------------------------------------
// Init: unpack u, s, v from X (per-sample stride 3*1024 floats);
// Xf0 = u s v^T (f32 + bf16 copies)
// ---------------------------------------------------------------------------
__global__ __launch_bounds__(256) void init_kernel(
    const float* __restrict__ X, float* __restrict__ u_g, float* __restrict__ v_g,
    float* __restrict__ s_g, float* __restrict__ Xf, u16* __restrict__ Xfb)
{
  const int b = blockIdx.x, t = threadIdx.x;
  __shared__ float U[64][17], V[64][17], S[16][16], P[64][17];
  const float* xb = X + (size_t)b * 3072;   // (3, 1024) per sample
  const size_t ub = (size_t)b << 10;
  {
    // u: (64,16) flat in xb[0..1023]
    const float4 u4 = *reinterpret_cast<const float4*>(xb + (t << 2));
    const int r = t >> 2, c = (t & 3) << 2;
    U[r][c] = u4.x; U[r][c + 1] = u4.y; U[r][c + 2] = u4.z; U[r][c + 3] = u4.w;
    *reinterpret_cast<float4*>(u_g + ub + (t << 2)) = u4;
    // s_core: top 16x16 of the (64,16) s_block -> flat idx r*16+c = t, at xb[1024+t]
    const float sv = xb[1024 + t];
    S[t >> 4][t & 15] = sv;
    s_g[((size_t)b << 8) + t] = sv;
    // vh: (16,64) flat in xb[2048..3071] -> v (64,16)
    const float4 v4 = *reinterpret_cast<const float4*>(xb + 2048 + (t << 2));
    const int g = t << 2;
    const int iv = g >> 6, q = g & 63;
    V[q][iv] = v4.x; V[q + 1][iv] = v4.y; V[q + 2][iv] = v4.z; V[q + 3][iv] = v4.w;
    v_g[ub + (size_t)q * 16 + iv] = v4.x;
    v_g[ub + (size_t)(q + 1) * 16 + iv] = v4.y;
    v_g[ub + (size_t)(q + 2) * 16 + iv] = v4.z;
    v_g[ub + (size_t)(q + 3) * 16 + iv] = v4.w;
  }
  __syncthreads();
  const int p4 = t >> 2, e4 = (t & 3) << 2;
#pragma unroll
  for (int e = 0; e < 4; ++e) {
    float a = 0.f;
    for (int i = 0; i < 16; ++i) a += U[p4][i] * S[i][e4 + e];
    P[p4][e4 + e] = a;
  }
  __syncthreads();
  {
    const int q0 = (t & 3) << 4;
    float res[16];
#pragma unroll
    for (int qq = 0; qq < 16; ++qq) {
      float a = 0.f;
      for (int i = 0; i < 16; ++i) a += P[p4][i] * V[q0 + qq][i];
      res[qq] = a;
    }
    const size_t ko = ((size_t)b << 12) + (p4 << 6) + q0;
    float4* xo = reinterpret_cast<float4*>(Xf + ko);
    xo[0] = make_float4(res[0], res[1], res[2], res[3]);
    xo[1] = make_float4(res[4], res[5], res[6], res[7]);
    xo[2] = make_float4(res[8], res[9], res[10], res[11]);
    xo[3] = make_float4(res[12], res[13], res[14], res[15]);
    uint4 pk0, pk1;
    pk0.x = pack2bf(res[0], res[1]);   pk0.y = pack2bf(res[2], res[3]);
    pk0.z = pack2bf(res[4], res[5]);   pk0.w = pack2bf(res[6], res[7]);
    pk1.x = pack2bf(res[8], res[9]);   pk1.y = pack2bf(res[10], res[11]);
    pk1.z = pack2bf(res[12], res[13]); pk1.w = pack2bf(res[14], res[15]);
    *reinterpret_cast<uint4*>(Xfb + ko) = pk0;
    *reinterpret_cast<uint4*>(Xfb + ko + 8) = pk1;
  }
}

// ---------------------------------------------------------------------------
// Classifier: logits = Xf @ Wc^T + bc ; softmax
// ---------------------------------------------------------------------------
__global__ __launch_bounds__(64) void classifier_kernel(
    const float* __restrict__ Xf, const float* __restrict__ Wc,
    const float* __restrict__ bc, float* __restrict__ pred, float* __restrict__ cls)
{
  const int b = blockIdx.x, l = threadIdx.x;
  float acc[10];
#pragma unroll
  for (int c = 0; c < 10; ++c) acc[c] = 0.f;
  const float* xr = Xf + ((size_t)b << 12);
  for (int k = l; k < 4096; k += 64) {
    const float x = xr[k];
#pragma unroll
    for (int c = 0; c < 10; ++c) acc[c] += x * Wc[c * 4096 + k];
  }
#pragma unroll
  for (int c = 0; c < 10; ++c)
    for (int off = 32; off; off >>= 1) acc[c] += __shfl_xor(acc[c], off);
  if (l == 0) {
    float lg[10], ex[10];
    float m = -1e30f;
#pragma unroll
    for (int c = 0; c < 10; ++c) { lg[c] = acc[c] + bc[c]; m = fmaxf(m, lg[c]); }
    float s = 0.f;
#pragma unroll
    for (int c = 0; c < 10; ++c) { ex[c] = expf(lg[c] - m); s += ex[c]; }
    const float inv = 1.f / s;
#pragma unroll
    for (int c = 0; c < 10; ++c) {
      cls[b * 10 + c] = lg[c];
      pred[b * 10 + c] = ex[c] * inv;
    }
  }
}

extern "C" void kernel_launch(void* const* d_in, const int* in_sizes, int n_in,
                              void* d_out, int out_size, void* d_ws, size_t ws_size,
                              hipStream_t stream) {
  (void)in_sizes; (void)n_in; (void)out_size; (void)ws_size;
  const float* X  = (const float*)d_in[0];
  const float* W0 = (const float*)d_in[1];
  const float* W  = (const float*)d_in[2];
  const float* bb = (const float*)d_in[3];
  const float* Wc = (const float*)d_in[4];
  const float* bc = (const float*)d_in[5];

  float* out_pred  = (float*)d_out;
  float* out_cls   = out_pred + 2560;
  float* out_trans = out_pred + 5120;

  char* ws = (char*)d_ws;
  float* Xf   = (float*)(ws);                      // 4 MB
  float* part = (float*)(ws + (4ull << 20));       // 16 MB (4 split-K partials)
  float* u_g  = (float*)(ws + (20ull << 20));      // 1 MB
  float* v_g  = (float*)(ws + (21ull << 20));      // 1 MB
  float* s_g  = (float*)(ws + (22ull << 20));      // 256 KB
  u16*   Xfb  = (u16*)  (ws + (23ull << 20));      // 2 MB

  init_kernel<<<NB, 256, 0, stream>>>(X, u_g, v_g, s_g, Xf, Xfb);
  for (int i = 0; i <= 8; ++i) {
    const float* Wl = (i == 0) ? W0 : W + (size_t)(i - 1) * DD * DD;
    gemm_kernel<<<dim3(64, SPLIT_K), 512, 0, stream>>>(Xfb, Wl, part);
    update_kernel<<<NB, 256, 0, stream>>>(
        part, (i == 0) ? nullptr : (bb + (size_t)(i - 1) * DD),
        u_g, v_g, s_g, Xf, Xfb, out_trans, i);
  }
  classifier_kernel<<<NB, 64, 0, stream>>>(Xf, Wc, bc, out_pred, out_cls);
}

// Round 3
// 534.801 us; speedup vs baseline: 1.0424x; 1.0424x over previous
//
#include <hip/hip_runtime.h>
#include <math.h>

typedef unsigned short u16;
using bf16x8 = __attribute__((ext_vector_type(8))) short;
using f32x4  = __attribute__((ext_vector_type(4))) float;

#define DD 4096
#define NB 256            // batch
#define SPLIT_K 4
#define PSTRIDE (NB * DD) // floats per partial buffer
#define PLANE (NB * DD)   // floats per transform layer plane

__device__ __forceinline__ u16 f2bf(float f) {
  unsigned int u = __float_as_uint(f);
  u += 0x7fffu + ((u >> 16) & 1u);   // RNE
  return (u16)(u >> 16);
}
__device__ __forceinline__ unsigned int pack2bf(float a, float b) {
  return (unsigned int)f2bf(a) | ((unsigned int)f2bf(b) << 16);
}
__device__ __forceinline__ void async_cp16(const u16* g, u16* l) {
  __builtin_amdgcn_global_load_lds(
      (const __attribute__((address_space(1))) unsigned int*)g,
      (__attribute__((address_space(3))) unsigned int*)l, 16, 0, 0);
}

// ---------------------------------------------------------------------------
// GEMM: part[kz] = Xf(bf16) @ W^T over K-chunk kz.  M=256 full per WG.
// grid (64 n-tiles, 4 k-splits), 512 threads (8 waves). Tile 256x64, BK=64.
// BW-bound pipeline: 2-deep prefetch (A triple-buffered LDS via
// global_load_lds, W->regs), raw s_barrier, counted vmcnt(12) — the memory
// pipe is never drained in the main loop.
// ---------------------------------------------------------------------------
__global__ __launch_bounds__(512) void gemm_kernel(
    const u16* __restrict__ A, const float* __restrict__ W,
    float* __restrict__ part)
{
  const int nt = blockIdx.x;
  const int kz = blockIdx.y;
  const int t = threadIdx.x;
  const int w = t >> 6, l = t & 63;

  __shared__ __align__(16) u16 As[3][256 * 64];   // 3 x 32 KB
  __shared__ __align__(16) u16 Bs[2][64 * 64];    // 2 x 8 KB

  const int colg0 = nt << 6;
  const int k0 = kz << 10;

  f32x4 acc[4][2];
#pragma unroll
  for (int mi = 0; mi < 4; ++mi)
#pragma unroll
    for (int nj = 0; nj < 2; ++nj)
      acc[mi][nj] = (f32x4){0.f, 0.f, 0.f, 0.f};

  const int wm = w & 3, wn = w >> 2;      // wave tile: rows 64*wm, cols 32*wn
  const int lr = l & 15, lg = l >> 4;
  const int arow_l = (w << 3) + (l >> 3); // A stage row (per rep +64)
  const int acl = l & 7;                  // linear chunk within row
  const int bn_l = t >> 3;                // B stage: W row (output col)
  const int bcc = t & 7;                  // B stage: chunk

  float4 bs0[3], bs1[3];

#define ISSUE_A(tt, buf) do {                                                \
    const int kkk = k0 + ((tt) << 6);                                        \
    _Pragma("unroll")                                                        \
    for (int r = 0; r < 4; ++r) {                                            \
      const int row = (r << 6) + arow_l;                                     \
      const int cs = acl ^ (row & 7);                                        \
      async_cp16(A + ((size_t)row << 12) + kkk + (cs << 3),                  \
                 &As[buf][(r << 12) + (w << 9)]);                            \
    } } while (0)

#define LOAD_B(tt, set) do {                                                 \
    const float* wsrc = W + ((size_t)(colg0 + bn_l) << 12) + k0 +            \
                        ((tt) << 6) + (bcc << 3);                            \
    bs0[set] = *reinterpret_cast<const float4*>(wsrc);                       \
    bs1[set] = *reinterpret_cast<const float4*>(wsrc + 4);                   \
  } while (0)

  ISSUE_A(0, 0); LOAD_B(0, 0);
  ISSUE_A(1, 1); LOAD_B(1, 1);

#pragma unroll
  for (int tt = 0; tt < 16; ++tt) {
    const int cb = tt % 3, nb = (tt + 2) % 3, pb = tt & 1;
    if (tt + 2 < 16) { ISSUE_A(tt + 2, nb); LOAD_B(tt + 2, nb); }
    // wait for A(tt) in LDS + B(tt) in regs; keep the 2 newer iters in flight
    if (tt < 14)       { asm volatile("s_waitcnt vmcnt(12)" ::: "memory"); }
    else if (tt == 14) { asm volatile("s_waitcnt vmcnt(6)"  ::: "memory"); }
    else               { asm volatile("s_waitcnt vmcnt(0)"  ::: "memory"); }
    __builtin_amdgcn_sched_barrier(0);
    // pack B(tt) fp32->bf16, swizzled ds_write
    {
      uint4 pk;
      pk.x = pack2bf(bs0[cb].x, bs0[cb].y);
      pk.y = pack2bf(bs0[cb].z, bs0[cb].w);
      pk.z = pack2bf(bs1[cb].x, bs1[cb].y);
      pk.w = pack2bf(bs1[cb].z, bs1[cb].w);
      *reinterpret_cast<uint4*>(&Bs[pb][(bn_l << 6) + ((bcc ^ (bn_l & 7)) << 3)]) = pk;
    }
    asm volatile("s_waitcnt lgkmcnt(0)" ::: "memory");
    __builtin_amdgcn_s_barrier();
    __builtin_amdgcn_sched_barrier(0);
#pragma unroll
    for (int ks = 0; ks < 2; ++ks) {
      const int cg = (ks << 2) + lg;
      bf16x8 av[4], bv[2];
#pragma unroll
      for (int mi = 0; mi < 4; ++mi) {
        const int fr = (wm << 6) + (mi << 4) + lr;
        av[mi] = *reinterpret_cast<const bf16x8*>(&As[cb][(fr << 6) + ((cg ^ (fr & 7)) << 3)]);
      }
#pragma unroll
      for (int nj = 0; nj < 2; ++nj) {
        const int fc = (wn << 5) + (nj << 4) + lr;
        bv[nj] = *reinterpret_cast<const bf16x8*>(&Bs[pb][(fc << 6) + ((cg ^ (fc & 7)) << 3)]);
      }
#pragma unroll
      for (int mi = 0; mi < 4; ++mi)
#pragma unroll
        for (int nj = 0; nj < 2; ++nj)
          acc[mi][nj] = __builtin_amdgcn_mfma_f32_16x16x32_bf16(
              av[mi], bv[nj], acc[mi][nj], 0, 0, 0);
    }
    __builtin_amdgcn_s_barrier();
  }
#undef ISSUE_A
#undef LOAD_B

  float* pout = part + (size_t)kz * PSTRIDE;
#pragma unroll
  for (int mi = 0; mi < 4; ++mi)
#pragma unroll
    for (int nj = 0; nj < 2; ++nj) {
      const int col = colg0 + (wn << 5) + (nj << 4) + lr;
#pragma unroll
      for (int j = 0; j < 4; ++j) {
        const int row = (wm << 6) + (mi << 4) + (lg << 2) + j;
        pout[((size_t)row << 12) + col] = acc[mi][nj][j];
      }
    }
}

// ---------------------------------------------------------------------------
// Per-sample Stiefel update.  Cayley collapsed analytically:
//   new_A = A - H^2 * F @ (A^T F) @ (A^T A)      (exact to fp32; H^4 ~ 1e-13)
// ---------------------------------------------------------------------------
__device__ __forceinline__ void stiefel_update(
    float (&Am)[64][17], float (&Dm)[64][17], float (&Fm)[64][17],
    float (&T1)[16][17], float (&G1)[16][17], float (&G2)[16][17],
    float (&M1)[16][17], int t, float* __restrict__ gout, size_t ub)
{
  const int p4 = t >> 2, e4 = (t & 3) << 2;
  const int i16 = t >> 4, j16 = t & 15;
  // T1 = A^T D
  {
    float a = 0.f;
    for (int r = 0; r < 64; ++r) a += Am[r][i16] * Dm[r][j16];
    T1[i16][j16] = a;
  }
  __syncthreads();
  // F = D - A @ T1
#pragma unroll
  for (int e = 0; e < 4; ++e) {
    float a = Dm[p4][e4 + e];
    for (int j = 0; j < 16; ++j) a -= Am[p4][j] * T1[j][e4 + e];
    Fm[p4][e4 + e] = a;
  }
  __syncthreads();
  // G1 = A^T F ; G2 = A^T A
  {
    float g1 = 0.f, g2 = 0.f;
    for (int r = 0; r < 64; ++r) {
      g1 += Am[r][i16] * Fm[r][j16];
      g2 += Am[r][i16] * Am[r][j16];
    }
    G1[i16][j16] = g1;
    G2[i16][j16] = g2;
  }
  __syncthreads();
  // M1 = G1 @ G2
  {
    float m = 0.f;
    for (int k = 0; k < 16; ++k) m += G1[i16][k] * G2[k][j16];
    M1[i16][j16] = m;
  }
  __syncthreads();
  // A -= H^2 * F @ M1
#pragma unroll
  for (int e = 0; e < 4; ++e) {
    float a = 0.f;
    for (int j = 0; j < 16; ++j) a += Fm[p4][j] * M1[j][e4 + e];
    const float nv = Am[p4][e4 + e] - 1e-6f * a;
    Am[p4][e4 + e] = nv;
    gout[ub + ((size_t)p4 << 4) + e4 + e] = nv;
  }
  __syncthreads();
}

__global__ __launch_bounds__(256) void update_kernel(
    const float* __restrict__ part, const float* __restrict__ bias,
    float* __restrict__ u_g, float* __restrict__ v_g, float* __restrict__ s_g,
    float* __restrict__ Xf, u16* __restrict__ Xfb,
    float* __restrict__ outL, int layer)
{
  const int b = blockIdx.x, t = threadIdx.x;
  __shared__ float dY[64][65];
  __shared__ float U[64][17], V[64][17];
  __shared__ float P[64][17], Q[64][17], F[64][17];
  __shared__ float S[16][16], dSs[16][17], T1[16][17], G1[16][17], G2[16][17], M1[16][17];
  __shared__ float sinv[16];

  const size_t ub = (size_t)b << 10;
  {
    const float4 u4 = *reinterpret_cast<const float4*>(u_g + ub + (t << 2));
    const float4 v4 = *reinterpret_cast<const float4*>(v_g + ub + (t << 2));
    const int r = t >> 2, c = (t & 3) << 2;
    U[r][c] = u4.x; U[r][c + 1] = u4.y; U[r][c + 2] = u4.z; U[r][c + 3] = u4.w;
    V[r][c] = v4.x; V[r][c + 1] = v4.y; V[r][c + 2] = v4.z; V[r][c + 3] = v4.w;
    S[t >> 4][t & 15] = s_g[((size_t)b << 8) + t];
  }
  __syncthreads();
  if (t < 16) sinv[t] = 1.0f / S[t][t];
  // dY = relu(sum of 4 partials + bias)
  {
    const float* p0 = part + ((size_t)b << 12);
#pragma unroll
    for (int it = 0; it < 4; ++it) {
      const int i = (it << 8) + t;  // float4 index 0..1023
      const float4 a0 = *reinterpret_cast<const float4*>(p0 + (i << 2));
      const float4 a1 = *reinterpret_cast<const float4*>(p0 + PSTRIDE + (i << 2));
      const float4 a2 = *reinterpret_cast<const float4*>(p0 + 2 * PSTRIDE + (i << 2));
      const float4 a3 = *reinterpret_cast<const float4*>(p0 + 3 * PSTRIDE + (i << 2));
      float x0 = a0.x + a1.x + a2.x + a3.x;
      float x1 = a0.y + a1.y + a2.y + a3.y;
      float x2 = a0.z + a1.z + a2.z + a3.z;
      float x3 = a0.w + a1.w + a2.w + a3.w;
      if (bias != nullptr) {
        const float4 bb = *reinterpret_cast<const float4*>(bias + (i << 2));
        x0 += bb.x; x1 += bb.y; x2 += bb.z; x3 += bb.w;
      }
      const int r = i >> 4, c = (i & 15) << 2;
      dY[r][c]     = fmaxf(x0, 0.f);
      dY[r][c + 1] = fmaxf(x1, 0.f);
      dY[r][c + 2] = fmaxf(x2, 0.f);
      dY[r][c + 3] = fmaxf(x3, 0.f);
    }
  }
  __syncthreads();
  const int p4 = t >> 2, e4 = (t & 3) << 2;
  const int i16 = t >> 4, j16 = t & 15;
  // P = dY @ V (Dv) ; Q = dY^T @ U (Du)
  {
    float a0 = 0, a1 = 0, a2 = 0, a3 = 0;
    for (int q = 0; q < 64; ++q) {
      const float d = dY[p4][q];
      a0 += d * V[q][e4]; a1 += d * V[q][e4 + 1];
      a2 += d * V[q][e4 + 2]; a3 += d * V[q][e4 + 3];
    }
    P[p4][e4] = a0; P[p4][e4 + 1] = a1; P[p4][e4 + 2] = a2; P[p4][e4 + 3] = a3;
    float b0 = 0, b1 = 0, b2 = 0, b3 = 0;
    for (int r = 0; r < 64; ++r) {
      const float d = dY[r][p4];
      b0 += d * U[r][e4]; b1 += d * U[r][e4 + 1];
      b2 += d * U[r][e4 + 2]; b3 += d * U[r][e4 + 3];
    }
    Q[p4][e4] = b0; Q[p4][e4 + 1] = b1; Q[p4][e4 + 2] = b2; Q[p4][e4 + 3] = b3;
  }
  __syncthreads();
  // dS = U^T @ P (unscaled Dv)
  {
    float a = 0.f;
    for (int r = 0; r < 64; ++r) a += U[r][i16] * P[r][j16];
    dSs[i16][j16] = a;
  }
  __syncthreads();
  // scale by s_inv diag: P -> dU, Q -> dV
  for (int i = t; i < 1024; i += 256) {
    const int r = i >> 4, c = i & 15;
    const float sc = sinv[c];
    P[r][c] *= sc;
    Q[r][c] *= sc;
  }
  __syncthreads();

  stiefel_update(U, P, F, T1, G1, G2, M1, t, u_g, ub);
  stiefel_update(V, Q, F, T1, G1, G2, M1, t, v_g, ub);

  // s += H * dS
  {
    const float ns = S[i16][j16] + 1e-3f * dSs[i16][j16];
    S[i16][j16] = ns;
    s_g[((size_t)b << 8) + t] = ns;
  }
  __syncthreads();
  // us = U @ S  (reuse P)
#pragma unroll
  for (int e = 0; e < 4; ++e) {
    float a = 0.f;
    for (int i = 0; i < 16; ++i) a += U[p4][i] * S[i][e4 + e];
    P[p4][e4 + e] = a;
  }
  __syncthreads();
  // Xf[p][q] = sum_i us[p][i] * V[q][i] ; write f32, bf16, contiguous layer plane
  {
    const int q0 = (t & 3) << 4;
    float res[16];
#pragma unroll
    for (int qq = 0; qq < 16; ++qq) {
      float a = 0.f;
      for (int i = 0; i < 16; ++i) a += P[p4][i] * V[q0 + qq][i];
      res[qq] = a;
    }
    const size_t ko = ((size_t)b << 12) + (p4 << 6) + q0;
    float4* xo = reinterpret_cast<float4*>(Xf + ko);
    xo[0] = make_float4(res[0], res[1], res[2], res[3]);
    xo[1] = make_float4(res[4], res[5], res[6], res[7]);
    xo[2] = make_float4(res[8], res[9], res[10], res[11]);
    xo[3] = make_float4(res[12], res[13], res[14], res[15]);
    uint4 pk0, pk1;
    pk0.x = pack2bf(res[0], res[1]);   pk0.y = pack2bf(res[2], res[3]);
    pk0.z = pack2bf(res[4], res[5]);   pk0.w = pack2bf(res[6], res[7]);
    pk1.x = pack2bf(res[8], res[9]);   pk1.y = pack2bf(res[10], res[11]);
    pk1.z = pack2bf(res[12], res[13]); pk1.w = pack2bf(res[14], res[15]);
    *reinterpret_cast<uint4*>(Xfb + ko) = pk0;
    *reinterpret_cast<uint4*>(Xfb + ko + 8) = pk1;
    float4* op = reinterpret_cast<float4*>(outL + (size_t)layer * PLANE + ko);
    op[0] = xo[0]; op[1] = xo[1]; op[2] = xo[2]; op[3] = xo[3];
  }
}

// ---------------------------------------------------------------------------
// Pack: outT[b,k,9] <- outL[9][b,k] via LDS, coalesced both sides.
// ---------------------------------------------------------------------------
__global__ __launch_bounds__(256) void pack_kernel(
    const float* __restrict__ outL, float* __restrict__ outT)
{
  const int t = threadIdx.x;
  const int base = blockIdx.x << 8;           // 256 (b,k) pairs per block
  __shared__ float buf[256 * 9];
#pragma unroll
  for (int l = 0; l < 9; ++l)
    buf[t * 9 + l] = outL[(size_t)l * PLANE + base + t];
  __syncthreads();
  const float4* b4 = reinterpret_cast<const float4*>(buf);
  float4* o4 = reinterpret_cast<float4*>(outT + (size_t)base * 9);
  for (int i = t; i < 576; i += 256) o4[i] = b4[i];
}

// ---------------------------------------------------------------------------
// Init: unpack u, s, v from X (per-sample stride 3*1024 floats);
// Xf0 = u s v^T (f32 + bf16 copies)
// ---------------------------------------------------------------------------
__global__ __launch_bounds__(256) void init_kernel(
    const float* __restrict__ X, float* __restrict__ u_g, float* __restrict__ v_g,
    float* __restrict__ s_g, float* __restrict__ Xf, u16* __restrict__ Xfb)
{
  const int b = blockIdx.x, t = threadIdx.x;
  __shared__ float U[64][17], V[64][17], S[16][16], P[64][17];
  const float* xb = X + (size_t)b * 3072;   // (3, 1024) per sample
  const size_t ub = (size_t)b << 10;
  {
    // u: (64,16) flat in xb[0..1023]
    const float4 u4 = *reinterpret_cast<const float4*>(xb + (t << 2));
    const int r = t >> 2, c = (t & 3) << 2;
    U[r][c] = u4.x; U[r][c + 1] = u4.y; U[r][c + 2] = u4.z; U[r][c + 3] = u4.w;
    *reinterpret_cast<float4*>(u_g + ub + (t << 2)) = u4;
    // s_core: top 16x16 of the (64,16) s_block -> flat idx t, at xb[1024+t]
    const float sv = xb[1024 + t];
    S[t >> 4][t & 15] = sv;
    s_g[((size_t)b << 8) + t] = sv;
    // vh: (16,64) flat in xb[2048..3071] -> v (64,16)
    const float4 v4 = *reinterpret_cast<const float4*>(xb + 2048 + (t << 2));
    const int g = t << 2;
    const int iv = g >> 6, q = g & 63;
    V[q][iv] = v4.x; V[q + 1][iv] = v4.y; V[q + 2][iv] = v4.z; V[q + 3][iv] = v4.w;
    v_g[ub + (size_t)q * 16 + iv] = v4.x;
    v_g[ub + (size_t)(q + 1) * 16 + iv] = v4.y;
    v_g[ub + (size_t)(q + 2) * 16 + iv] = v4.z;
    v_g[ub + (size_t)(q + 3) * 16 + iv] = v4.w;
  }
  __syncthreads();
  const int p4 = t >> 2, e4 = (t & 3) << 2;
#pragma unroll
  for (int e = 0; e < 4; ++e) {
    float a = 0.f;
    for (int i = 0; i < 16; ++i) a += U[p4][i] * S[i][e4 + e];
    P[p4][e4 + e] = a;
  }
  __syncthreads();
  {
    const int q0 = (t & 3) << 4;
    float res[16];
#pragma unroll
    for (int qq = 0; qq < 16; ++qq) {
      float a = 0.f;
      for (int i = 0; i < 16; ++i) a += P[p4][i] * V[q0 + qq][i];
      res[qq] = a;
    }
    const size_t ko = ((size_t)b << 12) + (p4 << 6) + q0;
    float4* xo = reinterpret_cast<float4*>(Xf + ko);
    xo[0] = make_float4(res[0], res[1], res[2], res[3]);
    xo[1] = make_float4(res[4], res[5], res[6], res[7]);
    xo[2] = make_float4(res[8], res[9], res[10], res[11]);
    xo[3] = make_float4(res[12], res[13], res[14], res[15]);
    uint4 pk0, pk1;
    pk0.x = pack2bf(res[0], res[1]);   pk0.y = pack2bf(res[2], res[3]);
    pk0.z = pack2bf(res[4], res[5]);   pk0.w = pack2bf(res[6], res[7]);
    pk1.x = pack2bf(res[8], res[9]);   pk1.y = pack2bf(res[10], res[11]);
    pk1.z = pack2bf(res[12], res[13]); pk1.w = pack2bf(res[14], res[15]);
    *reinterpret_cast<uint4*>(Xfb + ko) = pk0;
    *reinterpret_cast<uint4*>(Xfb + ko + 8) = pk1;
  }
}

// ---------------------------------------------------------------------------
// Classifier: logits = Xf @ Wc^T + bc ; softmax
// ---------------------------------------------------------------------------
__global__ __launch_bounds__(64) void classifier_kernel(
    const float* __restrict__ Xf, const float* __restrict__ Wc,
    const float* __restrict__ bc, float* __restrict__ pred, float* __restrict__ cls)
{
  const int b = blockIdx.x, l = threadIdx.x;
  float acc[10];
#pragma unroll
  for (int c = 0; c < 10; ++c) acc[c] = 0.f;
  const float* xr = Xf + ((size_t)b << 12);
  for (int k = l; k < 4096; k += 64) {
    const float x = xr[k];
#pragma unroll
    for (int c = 0; c < 10; ++c) acc[c] += x * Wc[c * 4096 + k];
  }
#pragma unroll
  for (int c = 0; c < 10; ++c)
    for (int off = 32; off; off >>= 1) acc[c] += __shfl_xor(acc[c], off);
  if (l == 0) {
    float lg[10], ex[10];
    float m = -1e30f;
#pragma unroll
    for (int c = 0; c < 10; ++c) { lg[c] = acc[c] + bc[c]; m = fmaxf(m, lg[c]); }
    float s = 0.f;
#pragma unroll
    for (int c = 0; c < 10; ++c) { ex[c] = expf(lg[c] - m); s += ex[c]; }
    const float inv = 1.f / s;
#pragma unroll
    for (int c = 0; c < 10; ++c) {
      cls[b * 10 + c] = lg[c];
      pred[b * 10 + c] = ex[c] * inv;
    }
  }
}

extern "C" void kernel_launch(void* const* d_in, const int* in_sizes, int n_in,
                              void* d_out, int out_size, void* d_ws, size_t ws_size,
                              hipStream_t stream) {
  (void)in_sizes; (void)n_in; (void)out_size; (void)ws_size;
  const float* X  = (const float*)d_in[0];
  const float* W0 = (const float*)d_in[1];
  const float* W  = (const float*)d_in[2];
  const float* bb = (const float*)d_in[3];
  const float* Wc = (const float*)d_in[4];
  const float* bc = (const float*)d_in[5];

  float* out_pred  = (float*)d_out;
  float* out_cls   = out_pred + 2560;
  float* out_trans = out_pred + 5120;

  char* ws = (char*)d_ws;
  float* Xf   = (float*)(ws);                      // 4 MB
  float* part = (float*)(ws + (4ull << 20));       // 16 MB (4 split-K partials)
  float* u_g  = (float*)(ws + (20ull << 20));      // 1 MB
  float* v_g  = (float*)(ws + (21ull << 20));      // 1 MB
  float* s_g  = (float*)(ws + (22ull << 20));      // 256 KB
  u16*   Xfb  = (u16*)  (ws + (23ull << 20));      // 2 MB
  float* outL = (float*)(ws + (25ull << 20));      // 36 MB (9 layer planes)

  init_kernel<<<NB, 256, 0, stream>>>(X, u_g, v_g, s_g, Xf, Xfb);
  for (int i = 0; i <= 8; ++i) {
    const float* Wl = (i == 0) ? W0 : W + (size_t)(i - 1) * DD * DD;
    gemm_kernel<<<dim3(64, SPLIT_K), 512, 0, stream>>>(Xfb, Wl, part);
    update_kernel<<<NB, 256, 0, stream>>>(
        part, (i == 0) ? nullptr : (bb + (size_t)(i - 1) * DD),
        u_g, v_g, s_g, Xf, Xfb, outL, i);
  }
  pack_kernel<<<4096, 256, 0, stream>>>(outL, out_trans);
  classifier_kernel<<<NB, 64, 0, stream>>>(Xf, Wc, bc, out_pred, out_cls);
}

// Round 4
// 487.051 us; speedup vs baseline: 1.1446x; 1.0980x over previous
//
#include <hip/hip_runtime.h>
#include <math.h>

typedef unsigned short u16;
typedef unsigned int u32;
using bf16x8 = __attribute__((ext_vector_type(8))) short;
using f32x4  = __attribute__((ext_vector_type(4))) float;

#define DD 4096
#define NB 256            // batch
#define SPLIT_K 4
#define PSTRIDE (NB * DD) // elements per partial buffer
#define PLANE (NB * DD)   // floats per transform layer plane

__device__ __forceinline__ u16 f2bf(float f) {
  unsigned int u = __float_as_uint(f);
  u += 0x7fffu + ((u >> 16) & 1u);   // RNE
  return (u16)(u >> 16);
}
__device__ __forceinline__ float bf2f(u16 h) {
  return __uint_as_float((u32)h << 16);
}
__device__ __forceinline__ unsigned int pack2bf(float a, float b) {
  return (unsigned int)f2bf(a) | ((unsigned int)f2bf(b) << 16);
}
__device__ __forceinline__ void async_cp16(const u16* g, u16* l) {
  __builtin_amdgcn_global_load_lds(
      (const __attribute__((address_space(1))) unsigned int*)g,
      (__attribute__((address_space(3))) unsigned int*)l, 16, 0, 0);
}

// ---------------------------------------------------------------------------
// GEMM: part[kz] = Xf(bf16) @ W^T over K-chunk kz, output bf16.
// grid (64 n-tiles, 4 k-splits), 512 threads. Tile 256x64, BK=64.
// 2-deep prefetch (A triple-buffered LDS via global_load_lds, W->regs),
// raw s_barrier, counted vmcnt — memory pipe never drained in main loop.
// ---------------------------------------------------------------------------
__global__ __launch_bounds__(512) void gemm_kernel(
    const u16* __restrict__ A, const float* __restrict__ W,
    u16* __restrict__ part)
{
  const int nt = blockIdx.x;
  const int kz = blockIdx.y;
  const int t = threadIdx.x;
  const int w = t >> 6, l = t & 63;

  __shared__ __align__(16) u16 As[3][256 * 64];   // 3 x 32 KB
  __shared__ __align__(16) u16 Bs[2][64 * 64];    // 2 x 8 KB

  const int colg0 = nt << 6;
  const int k0 = kz << 10;

  f32x4 acc[4][2];
#pragma unroll
  for (int mi = 0; mi < 4; ++mi)
#pragma unroll
    for (int nj = 0; nj < 2; ++nj)
      acc[mi][nj] = (f32x4){0.f, 0.f, 0.f, 0.f};

  const int wm = w & 3, wn = w >> 2;      // wave tile: rows 64*wm, cols 32*wn
  const int lr = l & 15, lg = l >> 4;
  const int arow_l = (w << 3) + (l >> 3); // A stage row (per rep +64)
  const int acl = l & 7;                  // linear chunk within row
  const int bn_l = t >> 3;                // B stage: W row (output col)
  const int bcc = t & 7;                  // B stage: chunk

  float4 bs0[3], bs1[3];

#define ISSUE_A(tt, buf) do {                                                \
    const int kkk = k0 + ((tt) << 6);                                        \
    _Pragma("unroll")                                                        \
    for (int r = 0; r < 4; ++r) {                                            \
      const int row = (r << 6) + arow_l;                                     \
      const int cs = acl ^ (row & 7);                                        \
      async_cp16(A + ((size_t)row << 12) + kkk + (cs << 3),                  \
                 &As[buf][(r << 12) + (w << 9)]);                            \
    } } while (0)

#define LOAD_B(tt, set) do {                                                 \
    const float* wsrc = W + ((size_t)(colg0 + bn_l) << 12) + k0 +            \
                        ((tt) << 6) + (bcc << 3);                            \
    bs0[set] = *reinterpret_cast<const float4*>(wsrc);                       \
    bs1[set] = *reinterpret_cast<const float4*>(wsrc + 4);                   \
  } while (0)

  ISSUE_A(0, 0); LOAD_B(0, 0);
  ISSUE_A(1, 1); LOAD_B(1, 1);

#pragma unroll
  for (int tt = 0; tt < 16; ++tt) {
    const int cb = tt % 3, nb = (tt + 2) % 3, pb = tt & 1;
    if (tt + 2 < 16) { ISSUE_A(tt + 2, nb); LOAD_B(tt + 2, nb); }
    if (tt < 14)       { asm volatile("s_waitcnt vmcnt(12)" ::: "memory"); }
    else if (tt == 14) { asm volatile("s_waitcnt vmcnt(6)"  ::: "memory"); }
    else               { asm volatile("s_waitcnt vmcnt(0)"  ::: "memory"); }
    __builtin_amdgcn_sched_barrier(0);
    {
      uint4 pk;
      pk.x = pack2bf(bs0[cb].x, bs0[cb].y);
      pk.y = pack2bf(bs0[cb].z, bs0[cb].w);
      pk.z = pack2bf(bs1[cb].x, bs1[cb].y);
      pk.w = pack2bf(bs1[cb].z, bs1[cb].w);
      *reinterpret_cast<uint4*>(&Bs[pb][(bn_l << 6) + ((bcc ^ (bn_l & 7)) << 3)]) = pk;
    }
    asm volatile("s_waitcnt lgkmcnt(0)" ::: "memory");
    __builtin_amdgcn_s_barrier();
    __builtin_amdgcn_sched_barrier(0);
#pragma unroll
    for (int ks = 0; ks < 2; ++ks) {
      const int cg = (ks << 2) + lg;
      bf16x8 av[4], bv[2];
#pragma unroll
      for (int mi = 0; mi < 4; ++mi) {
        const int fr = (wm << 6) + (mi << 4) + lr;
        av[mi] = *reinterpret_cast<const bf16x8*>(&As[cb][(fr << 6) + ((cg ^ (fr & 7)) << 3)]);
      }
#pragma unroll
      for (int nj = 0; nj < 2; ++nj) {
        const int fc = (wn << 5) + (nj << 4) + lr;
        bv[nj] = *reinterpret_cast<const bf16x8*>(&Bs[pb][(fc << 6) + ((cg ^ (fc & 7)) << 3)]);
      }
#pragma unroll
      for (int mi = 0; mi < 4; ++mi)
#pragma unroll
        for (int nj = 0; nj < 2; ++nj)
          acc[mi][nj] = __builtin_amdgcn_mfma_f32_16x16x32_bf16(
              av[mi], bv[nj], acc[mi][nj], 0, 0, 0);
    }
    __builtin_amdgcn_s_barrier();
  }
#undef ISSUE_A
#undef LOAD_B

  u16* pout = part + (size_t)kz * PSTRIDE;
#pragma unroll
  for (int mi = 0; mi < 4; ++mi)
#pragma unroll
    for (int nj = 0; nj < 2; ++nj) {
      const int col = colg0 + (wn << 5) + (nj << 4) + lr;
#pragma unroll
      for (int j = 0; j < 4; ++j) {
        const int row = (wm << 6) + (mi << 4) + (lg << 2) + j;
        pout[((size_t)row << 12) + col] = f2bf(acc[mi][nj][j]);
      }
    }
}

// ---------------------------------------------------------------------------
// Per-sample fused update, 512 threads. Cayley collapsed analytically:
//   new_A = A - H^2 * F @ (A^T F) @ (A^T A)   (exact to fp32; H^4 ~ 1e-13)
// All 64-deep reductions parallelized across 512 threads.
// ---------------------------------------------------------------------------
__device__ __forceinline__ void stiefel_update512(
    float (&Am)[64][17], float (&Dm)[64][17], float (&Fm)[64][17],
    float (&T1)[16][17], float (&G1)[16][17], float (&G2)[16][17],
    float (&M1)[16][17], float (&RS)[512],
    int t, float* __restrict__ gout, size_t ub)
{
  const int p = t >> 3;              // 0..63
  const int j0 = (t << 1) & 15;      // even col
  // T1 = A^T D (split-2 over rows)
  {
    const int half = t & 1, i = t >> 5, j = (t >> 1) & 15;
    float a = 0.f;
    const int r0 = half << 5;
    for (int r = r0; r < r0 + 32; ++r) a += Am[r][i] * Dm[r][j];
    RS[t] = a;
  }
  __syncthreads();
  if (t < 256) T1[t >> 4][t & 15] = RS[t << 1] + RS[(t << 1) + 1];
  __syncthreads();
  // F = D - A @ T1   (2 outputs per thread)
  {
    float f0 = Dm[p][j0], f1 = Dm[p][j0 + 1];
    for (int k = 0; k < 16; ++k) {
      const float ak = Am[p][k];
      f0 -= ak * T1[k][j0];
      f1 -= ak * T1[k][j0 + 1];
    }
    Fm[p][j0] = f0; Fm[p][j0 + 1] = f1;
  }
  __syncthreads();
  // G1 = A^T F (waves 0-3) ; G2 = A^T A (waves 4-7)
  if (t < 256) {
    const int i = t >> 4, j = t & 15;
    float g = 0.f;
    for (int r = 0; r < 64; ++r) g += Am[r][i] * Fm[r][j];
    G1[i][j] = g;
  } else {
    const int tt = t - 256, i = tt >> 4, j = tt & 15;
    float g = 0.f;
    for (int r = 0; r < 64; ++r) g += Am[r][i] * Am[r][j];
    G2[i][j] = g;
  }
  __syncthreads();
  // M1 = G1 @ G2
  if (t < 256) {
    const int i = t >> 4, j = t & 15;
    float m = 0.f;
    for (int k = 0; k < 16; ++k) m += G1[i][k] * G2[k][j];
    M1[i][j] = m;
  }
  __syncthreads();
  // A -= H^2 * F @ M1  (2 outputs per thread; stash, sync, write)
  {
    float a0 = 0.f, a1 = 0.f;
    for (int k = 0; k < 16; ++k) {
      const float fk = Fm[p][k];
      a0 += fk * M1[k][j0];
      a1 += fk * M1[k][j0 + 1];
    }
    const float n0 = Am[p][j0] - 1e-6f * a0;
    const float n1 = Am[p][j0 + 1] - 1e-6f * a1;
    __syncthreads();
    Am[p][j0] = n0; Am[p][j0 + 1] = n1;
    *reinterpret_cast<float2*>(gout + ub + (p << 4) + j0) = make_float2(n0, n1);
  }
  __syncthreads();
}

__global__ __launch_bounds__(512) void update_kernel(
    const u16* __restrict__ part, const float* __restrict__ bias,
    float* __restrict__ u_g, float* __restrict__ v_g, float* __restrict__ s_g,
    float* __restrict__ Xf, u16* __restrict__ Xfb,
    float* __restrict__ outL, int layer)
{
  const int b = blockIdx.x, t = threadIdx.x;
  __shared__ float dY[64][68];
  __shared__ float U[64][17], V[64][17];
  __shared__ float P[64][17], Q[64][17], F[64][17];
  __shared__ float S[16][16], dSs[16][17], T1[16][17], G1[16][17], G2[16][17], M1[16][17];
  __shared__ float sinv[16];
  __shared__ float RS[512];

  const size_t ub = (size_t)b << 10;
  {
    const float2 u2 = *reinterpret_cast<const float2*>(u_g + ub + (t << 1));
    const float2 v2 = *reinterpret_cast<const float2*>(v_g + ub + (t << 1));
    const int r = t >> 3, c = (t & 7) << 1;
    U[r][c] = u2.x; U[r][c + 1] = u2.y;
    V[r][c] = v2.x; V[r][c + 1] = v2.y;
    if (t < 256) S[t >> 4][t & 15] = s_g[((size_t)b << 8) + t];
  }
  __syncthreads();
  if (t < 16) sinv[t] = 1.0f / S[t][t];
  // dY = relu(sum of 4 bf16 partials + bias); 8 elems per thread
  {
    const u16* p0 = part + ((size_t)b << 12) + (t << 3);
    float x[8];
#pragma unroll
    for (int e = 0; e < 8; ++e) x[e] = 0.f;
#pragma unroll
    for (int kzi = 0; kzi < 4; ++kzi) {
      const uint4 v = *reinterpret_cast<const uint4*>(p0 + (size_t)kzi * PSTRIDE);
      x[0] += bf2f((u16)(v.x & 0xffff)); x[1] += bf2f((u16)(v.x >> 16));
      x[2] += bf2f((u16)(v.y & 0xffff)); x[3] += bf2f((u16)(v.y >> 16));
      x[4] += bf2f((u16)(v.z & 0xffff)); x[5] += bf2f((u16)(v.z >> 16));
      x[6] += bf2f((u16)(v.w & 0xffff)); x[7] += bf2f((u16)(v.w >> 16));
    }
    if (bias != nullptr) {
      const float4 b0 = *reinterpret_cast<const float4*>(bias + (t << 3));
      const float4 b1 = *reinterpret_cast<const float4*>(bias + (t << 3) + 4);
      x[0] += b0.x; x[1] += b0.y; x[2] += b0.z; x[3] += b0.w;
      x[4] += b1.x; x[5] += b1.y; x[6] += b1.z; x[7] += b1.w;
    }
    const int r = t >> 3, c = (t & 7) << 3;
    float4* d0 = reinterpret_cast<float4*>(&dY[r][c]);
    d0[0] = make_float4(fmaxf(x[0], 0.f), fmaxf(x[1], 0.f), fmaxf(x[2], 0.f), fmaxf(x[3], 0.f));
    d0[1] = make_float4(fmaxf(x[4], 0.f), fmaxf(x[5], 0.f), fmaxf(x[6], 0.f), fmaxf(x[7], 0.f));
  }
  __syncthreads();
  const int p = t >> 3;              // 0..63
  const int j0 = (t << 1) & 15;      // even col
  // P = dY @ V ; Q = dY^T @ U   (2 outputs per thread each)
  {
    float a0 = 0.f, a1 = 0.f;
    for (int q = 0; q < 64; ++q) {
      const float d = dY[p][q];
      a0 += d * V[q][j0];
      a1 += d * V[q][j0 + 1];
    }
    P[p][j0] = a0; P[p][j0 + 1] = a1;
    float b0 = 0.f, b1 = 0.f;
    for (int r = 0; r < 64; ++r) {
      const float d = dY[r][p];
      b0 += d * U[r][j0];
      b1 += d * U[r][j0 + 1];
    }
    Q[p][j0] = b0; Q[p][j0 + 1] = b1;
  }
  __syncthreads();
  // dS = U^T @ P (unscaled), split-2
  {
    const int half = t & 1, i = t >> 5, j = (t >> 1) & 15;
    float a = 0.f;
    const int r0 = half << 5;
    for (int r = r0; r < r0 + 32; ++r) a += U[r][i] * P[r][j];
    RS[t] = a;
  }
  __syncthreads();
  if (t < 256) dSs[t >> 4][t & 15] = RS[t << 1] + RS[(t << 1) + 1];
  __syncthreads();
  // scale P,Q cols by sinv
  for (int i = t; i < 1024; i += 512) {
    const int r = i >> 4, c = i & 15;
    const float sc = sinv[c];
    P[r][c] *= sc;
    Q[r][c] *= sc;
  }
  __syncthreads();

  stiefel_update512(U, P, F, T1, G1, G2, M1, RS, t, u_g, ub);
  stiefel_update512(V, Q, F, T1, G1, G2, M1, RS, t, v_g, ub);

  // s += H * dS
  if (t < 256) {
    const int i = t >> 4, j = t & 15;
    const float ns = S[i][j] + 1e-3f * dSs[i][j];
    S[i][j] = ns;
    s_g[((size_t)b << 8) + t] = ns;
  }
  __syncthreads();
  // us = U @ S  (into P)
  {
    float a0 = 0.f, a1 = 0.f;
    for (int k = 0; k < 16; ++k) {
      const float uk = U[p][k];
      a0 += uk * S[k][j0];
      a1 += uk * S[k][j0 + 1];
    }
    P[p][j0] = a0; P[p][j0 + 1] = a1;
  }
  __syncthreads();
  // Xf[p][q] = sum_i us[p][i] * V[q][i] ; 8 outputs per thread
  {
    const int q0 = (t & 7) << 3;
    float res[8];
#pragma unroll
    for (int e = 0; e < 8; ++e) res[e] = 0.f;
    for (int i = 0; i < 16; ++i) {
      const float pi = P[p][i];
#pragma unroll
      for (int e = 0; e < 8; ++e) res[e] += pi * V[q0 + e][i];
    }
    const size_t ko = ((size_t)b << 12) + (p << 6) + q0;
    float4* xo = reinterpret_cast<float4*>(Xf + ko);
    xo[0] = make_float4(res[0], res[1], res[2], res[3]);
    xo[1] = make_float4(res[4], res[5], res[6], res[7]);
    uint4 pk;
    pk.x = pack2bf(res[0], res[1]); pk.y = pack2bf(res[2], res[3]);
    pk.z = pack2bf(res[4], res[5]); pk.w = pack2bf(res[6], res[7]);
    *reinterpret_cast<uint4*>(Xfb + ko) = pk;
    float4* op = reinterpret_cast<float4*>(outL + (size_t)layer * PLANE + ko);
    op[0] = xo[0]; op[1] = xo[1];
  }
}

// ---------------------------------------------------------------------------
// Pack: outT[b,k,9] <- outL[9][b,k] via LDS, coalesced both sides.
// ---------------------------------------------------------------------------
__global__ __launch_bounds__(256) void pack_kernel(
    const float* __restrict__ outL, float* __restrict__ outT)
{
  const int t = threadIdx.x;
  const int base = blockIdx.x << 8;           // 256 (b,k) pairs per block
  __shared__ float buf[256 * 9];
#pragma unroll
  for (int l = 0; l < 9; ++l)
    buf[t * 9 + l] = outL[(size_t)l * PLANE + base + t];
  __syncthreads();
  const float4* b4 = reinterpret_cast<const float4*>(buf);
  float4* o4 = reinterpret_cast<float4*>(outT + (size_t)base * 9);
  for (int i = t; i < 576; i += 256) o4[i] = b4[i];
}

// ---------------------------------------------------------------------------
// Init: unpack u, s, v from X (per-sample stride 3*1024 floats);
// Xf0 = u s v^T (f32 + bf16 copies)
// ---------------------------------------------------------------------------
__global__ __launch_bounds__(256) void init_kernel(
    const float* __restrict__ X, float* __restrict__ u_g, float* __restrict__ v_g,
    float* __restrict__ s_g, float* __restrict__ Xf, u16* __restrict__ Xfb)
{
  const int b = blockIdx.x, t = threadIdx.x;
  __shared__ float U[64][17], V[64][17], S[16][16], P[64][17];
  const float* xb = X + (size_t)b * 3072;   // (3, 1024) per sample
  const size_t ub = (size_t)b << 10;
  {
    const float4 u4 = *reinterpret_cast<const float4*>(xb + (t << 2));
    const int r = t >> 2, c = (t & 3) << 2;
    U[r][c] = u4.x; U[r][c + 1] = u4.y; U[r][c + 2] = u4.z; U[r][c + 3] = u4.w;
    *reinterpret_cast<float4*>(u_g + ub + (t << 2)) = u4;
    const float sv = xb[1024 + t];
    S[t >> 4][t & 15] = sv;
    s_g[((size_t)b << 8) + t] = sv;
    const float4 v4 = *reinterpret_cast<const float4*>(xb + 2048 + (t << 2));
    const int g = t << 2;
    const int iv = g >> 6, q = g & 63;
    V[q][iv] = v4.x; V[q + 1][iv] = v4.y; V[q + 2][iv] = v4.z; V[q + 3][iv] = v4.w;
    v_g[ub + (size_t)q * 16 + iv] = v4.x;
    v_g[ub + (size_t)(q + 1) * 16 + iv] = v4.y;
    v_g[ub + (size_t)(q + 2) * 16 + iv] = v4.z;
    v_g[ub + (size_t)(q + 3) * 16 + iv] = v4.w;
  }
  __syncthreads();
  const int p4 = t >> 2, e4 = (t & 3) << 2;
#pragma unroll
  for (int e = 0; e < 4; ++e) {
    float a = 0.f;
    for (int i = 0; i < 16; ++i) a += U[p4][i] * S[i][e4 + e];
    P[p4][e4 + e] = a;
  }
  __syncthreads();
  {
    const int q0 = (t & 3) << 4;
    float res[16];
#pragma unroll
    for (int qq = 0; qq < 16; ++qq) {
      float a = 0.f;
      for (int i = 0; i < 16; ++i) a += P[p4][i] * V[q0 + qq][i];
      res[qq] = a;
    }
    const size_t ko = ((size_t)b << 12) + (p4 << 6) + q0;
    float4* xo = reinterpret_cast<float4*>(Xf + ko);
    xo[0] = make_float4(res[0], res[1], res[2], res[3]);
    xo[1] = make_float4(res[4], res[5], res[6], res[7]);
    xo[2] = make_float4(res[8], res[9], res[10], res[11]);
    xo[3] = make_float4(res[12], res[13], res[14], res[15]);
    uint4 pk0, pk1;
    pk0.x = pack2bf(res[0], res[1]);   pk0.y = pack2bf(res[2], res[3]);
    pk0.z = pack2bf(res[4], res[5]);   pk0.w = pack2bf(res[6], res[7]);
    pk1.x = pack2bf(res[8], res[9]);   pk1.y = pack2bf(res[10], res[11]);
    pk1.z = pack2bf(res[12], res[13]); pk1.w = pack2bf(res[14], res[15]);
    *reinterpret_cast<uint4*>(Xfb + ko) = pk0;
    *reinterpret_cast<uint4*>(Xfb + ko + 8) = pk1;
  }
}

// ---------------------------------------------------------------------------
// Classifier: logits = Xf @ Wc^T + bc ; softmax.  256 threads/block.
// ---------------------------------------------------------------------------
__global__ __launch_bounds__(256) void classifier_kernel(
    const float* __restrict__ Xf, const float* __restrict__ Wc,
    const float* __restrict__ bc, float* __restrict__ pred, float* __restrict__ cls)
{
  const int b = blockIdx.x, t = threadIdx.x;
  const int lane = t & 63, w = t >> 6;
  __shared__ float red[4][10];
  float acc[10];
#pragma unroll
  for (int c = 0; c < 10; ++c) acc[c] = 0.f;
  const float* xr = Xf + ((size_t)b << 12);
  for (int k = t; k < 4096; k += 256) {
    const float x = xr[k];
#pragma unroll
    for (int c = 0; c < 10; ++c) acc[c] += x * Wc[c * 4096 + k];
  }
#pragma unroll
  for (int c = 0; c < 10; ++c)
    for (int off = 32; off; off >>= 1) acc[c] += __shfl_xor(acc[c], off);
  if (lane == 0)
#pragma unroll
    for (int c = 0; c < 10; ++c) red[w][c] = acc[c];
  __syncthreads();
  if (t == 0) {
    float lg[10], ex[10];
    float m = -1e30f;
#pragma unroll
    for (int c = 0; c < 10; ++c) {
      lg[c] = red[0][c] + red[1][c] + red[2][c] + red[3][c] + bc[c];
      m = fmaxf(m, lg[c]);
    }
    float s = 0.f;
#pragma unroll
    for (int c = 0; c < 10; ++c) { ex[c] = expf(lg[c] - m); s += ex[c]; }
    const float inv = 1.f / s;
#pragma unroll
    for (int c = 0; c < 10; ++c) {
      cls[b * 10 + c] = lg[c];
      pred[b * 10 + c] = ex[c] * inv;
    }
  }
}

extern "C" void kernel_launch(void* const* d_in, const int* in_sizes, int n_in,
                              void* d_out, int out_size, void* d_ws, size_t ws_size,
                              hipStream_t stream) {
  (void)in_sizes; (void)n_in; (void)out_size; (void)ws_size;
  const float* X  = (const float*)d_in[0];
  const float* W0 = (const float*)d_in[1];
  const float* W  = (const float*)d_in[2];
  const float* bb = (const float*)d_in[3];
  const float* Wc = (const float*)d_in[4];
  const float* bc = (const float*)d_in[5];

  float* out_pred  = (float*)d_out;
  float* out_cls   = out_pred + 2560;
  float* out_trans = out_pred + 5120;

  char* ws = (char*)d_ws;
  float* Xf   = (float*)(ws);                      // 4 MB
  u16*   part = (u16*)  (ws + (4ull << 20));       // 8 MB (4 bf16 split-K partials)
  float* u_g  = (float*)(ws + (20ull << 20));      // 1 MB
  float* v_g  = (float*)(ws + (21ull << 20));      // 1 MB
  float* s_g  = (float*)(ws + (22ull << 20));      // 256 KB
  u16*   Xfb  = (u16*)  (ws + (23ull << 20));      // 2 MB
  float* outL = (float*)(ws + (25ull << 20));      // 36 MB (9 layer planes)

  init_kernel<<<NB, 256, 0, stream>>>(X, u_g, v_g, s_g, Xf, Xfb);
  for (int i = 0; i <= 8; ++i) {
    const float* Wl = (i == 0) ? W0 : W + (size_t)(i - 1) * DD * DD;
    gemm_kernel<<<dim3(64, SPLIT_K), 512, 0, stream>>>(Xfb, Wl, part);
    update_kernel<<<NB, 512, 0, stream>>>(
        part, (i == 0) ? nullptr : (bb + (size_t)(i - 1) * DD),
        u_g, v_g, s_g, Xf, Xfb, outL, i);
  }
  pack_kernel<<<4096, 256, 0, stream>>>(outL, out_trans);
  classifier_kernel<<<NB, 256, 0, stream>>>(Xf, Wc, bc, out_pred, out_cls);
}